// Round 11
// baseline (229.846 us; speedup 1.0000x reference)
//
#include <hip/hip_runtime.h>
#include <cstddef>

// StreamingISTFT fully fused: pair-load + denorm + Hermitian-pack at the
// LOADER -> full staged W (64 KB, ONE barrier) -> FFT32(k2) -> LDS transpose
// -> FFT32(k1) -> window -> LDS frame tile -> overlap-add -> stores.
// B=8, F=1024(+Nyquist), T=2048, HOP=512, L=2048.
// irfft(2048) = complex IFFT(1024) (real-packing); IFFT(1024) = 32x32 four-step.
//
// R8:  XCD-aware remap: FETCH 446->67 MB.
// R11: staged float4 input: 100->85 us.
// R12/R13/R16: occupancy campaigns all REGRESSED (110-117 us).
// R15: LDS-instruction halving: null. R17: consumer pack VALU removal: null.
// => neither work terms nor residency are the limiter; the serial convoy is.
// R18: single-shot staging. Key fact (documented hipcc behavior): every
//      __syncthreads drains vmcnt(0) -- so R11-R17's "B loads in flight
//      across the barrier" never pipelined; stage 1 paid 2 full HBM
//      exposures + 4 barrier convoys, serially. Staged W is 1024 slots x
//      8t x complex = 64 KB and FITS the R14 budget: load all 4 mirror-
//      paired rows/thread (16 float4, ONE exposure), denorm+pack at loader
//      (R17-proven math), store W, ONE barrier, consumer reads 32 b64
//      (no superchunks, no q=0 case). Barriers 7 -> 5. Pair cover: t=0 ->
//      {DC 0, self 512, (256,768)}; t>=1 -> (t,1024-t),(256+t,768-t).
//      Store rotation (tid>>1)&3 -> b128 at bank floor; reads at floor.
//      LDS (67.6 KB -> 2 blocks/CU) dominates VGPR, so fatter threads are
//      occupancy-free. Transpose/F/OLA = R14 verbatim (proven 85 us).

#define TDIM 2048
#define FDIM 1024
#define TT 8                    // t-columns per block
#define NTOT (512 * 2048)       // output samples per batch

static constexpr int kBREV[32] = {0,16,8,24,4,20,12,28,2,18,10,26,6,22,14,30,
                                  1,17,9,25,5,21,13,29,3,19,11,27,7,23,15,31};
// e^{+2*pi*i*r/32}, r=0..15 (inverse-transform sign)
static constexpr float kTR[16] = {
  1.0f, 0.98078528040323044f, 0.92387953251128674f, 0.83146961230254524f,
  0.70710678118654757f, 0.55557023301960218f, 0.38268343236508978f, 0.19509032201612825f,
  0.0f, -0.19509032201612825f, -0.38268343236508978f, -0.55557023301960218f,
  -0.70710678118654757f, -0.83146961230254524f, -0.92387953251128674f, -0.98078528040323044f};
static constexpr float kTI[16] = {
  0.0f, 0.19509032201612825f, 0.38268343236508978f, 0.55557023301960218f,
  0.70710678118654757f, 0.83146961230254524f, 0.92387953251128674f, 0.98078528040323044f,
  1.0f, 0.98078528040323044f, 0.92387953251128674f, 0.83146961230254524f,
  0.70710678118654757f, 0.55557023301960218f, 0.38268343236508978f, 0.19509032201612825f};

template <int H>
__device__ __forceinline__ void fft32_stage(float ar[32], float ai[32]) {
  constexpr int TSTEP = 16 / H;
  #pragma unroll
  for (int g = 0; g < 32; g += 2 * H) {
    #pragma unroll
    for (int j = 0; j < H; ++j) {
      const float twr = kTR[j * TSTEP];
      const float twi = kTI[j * TSTEP];
      const int i0 = g + j, i1 = i0 + H;
      const float tr = twr * ar[i1] - twi * ai[i1];
      const float ti = twr * ai[i1] + twi * ar[i1];
      ar[i1] = ar[i0] - tr; ai[i1] = ai[i0] - ti;
      ar[i0] += tr;         ai[i0] += ti;
    }
  }
}

// In-register radix-2 DIT FFT32 (inverse sign). Input bit-reversed; out natural.
__device__ __forceinline__ void ifft32_core(float ar[32], float ai[32]) {
  fft32_stage<1>(ar, ai);
  fft32_stage<2>(ar, ai);
  fft32_stage<4>(ar, ai);
  fft32_stage<8>(ar, ai);
  fft32_stage<16>(ar, ai);
}

// |v|^(2*PE) * KS via native v_log_f32 + v_exp_f32. v=0 -> 0: ok.
__device__ __forceinline__ float pow_gain(float v, float PE, float KS) {
  return KS * __builtin_amdgcn_exp2f(PE * __builtin_amdgcn_logf(v));
}

__device__ __forceinline__ void denorm4(float4& r, float4& i, float PE, float KS) {
  float g;
  g = pow_gain(r.x * r.x + i.x * i.x, PE, KS); r.x *= g; i.x *= g;
  g = pow_gain(r.y * r.y + i.y * i.y, PE, KS); r.y *= g; i.y *= g;
  g = pow_gain(r.z * r.z + i.z * i.z, PE, KS); r.z *= g; i.z *= g;
  g = pow_gain(r.w * r.w + i.w * i.w, PE, KS); r.w *= g; i.w *= g;
}

__device__ __forceinline__ void unpack8(const float4 v[2], float o[8]) {
  o[0]=v[0].x; o[1]=v[0].y; o[2]=v[0].z; o[3]=v[0].w;
  o[4]=v[1].x; o[5]=v[1].y; o[6]=v[1].z; o[7]=v[1].w;
}

// Store one W row (8 complex, interleaved) at slot j: 4 b128 with per-thread
// m-rotation so a wave's stores spread over all 8 bank-quads (b128 floor).
__device__ __forceinline__ void store_row(float* __restrict__ S, int j,
                                          const float w[16], int rot) {
  #pragma unroll
  for (int m = 0; m < 4; ++m) {
    const int mm = (m + rot) & 3;
    *(float4*)(S + j * 16 + 4 * mm) =
        make_float4(w[4*mm], w[4*mm+1], w[4*mm+2], w[4*mm+3]);
  }
}

// Pack a mirror pair of denormed rows a=S[ja], b=S[1024-ja] (8 t's each):
// W[ja] = (Pre-u, Pim+v), W[1024-ja] = (Pre+u, v-Pim), T = e^{i pi ja/1024}.
// (Math proven in R17; self-pair ja=jb=512 yields Wa==Wb, double-store ok.)
__device__ __forceinline__ void pack_pair8(float* __restrict__ S, int ja, int jb,
    const float4 ar4[2], const float4 ai4[2],
    const float4 br4[2], const float4 bi4[2], int rot) {
  float a_r[8], a_i[8], b_r[8], b_i[8];
  unpack8(ar4, a_r); unpack8(ai4, a_i); unpack8(br4, b_r); unpack8(bi4, b_i);
  const float ang = 3.0679615757712824e-3f * (float)ja;
  const float ca = __cosf(ang), sn = __sinf(ang);
  float wa[16], wb[16];
  #pragma unroll
  for (int t = 0; t < 8; ++t) {
    const float Pre = a_r[t] + b_r[t], Pim = a_i[t] - b_i[t];
    const float Qre = a_r[t] - b_r[t], Qim = a_i[t] + b_i[t];
    const float u = ca * Qim + sn * Qre;
    const float v = ca * Qre - sn * Qim;
    wa[2*t] = Pre - u;  wa[2*t+1] = Pim + v;
    wb[2*t] = Pre + u;  wb[2*t+1] = v - Pim;
  }
  store_row(S, ja, wa, rot);
  store_row(S, jb, wb, rot);
}

// DC (k=0): Im of spec[0] dropped, Nyquist = 0 -> W[0] = re + i*re.
__device__ __forceinline__ void dc8(float* __restrict__ S,
                                    const float4 r4[2], int rot) {
  float r[8]; unpack8(r4, r);
  float w[16];
  #pragma unroll
  for (int t = 0; t < 8; ++t) { w[2*t] = r[t]; w[2*t+1] = r[t]; }
  store_row(S, 0, w, rot);
}

// Full-X layout: X(t, k1, r) = k1*264 + r*8 + t (264 = 32*8 + 8 pad).
// Write banks (8k1+t+8r) -> 2-way; read banks (8r+t+8k1) -> 2-way. Max 8439.
#define XIDX(t, k1, r) ((k1) * 264 + (r) * 8 + (t))
#define FSTR 2054               // frame tile row stride (even: float2 writes)

__global__ __launch_bounds__(256) void istft_fused(const float* __restrict__ in,
                                                   const float* __restrict__ invw,
                                                   float* __restrict__ out) {
  __shared__ float buf[16896];          // 67.6 KB, three overlapped tenants:
  float* Sri = buf;                     //  W staging: [0,16384)
  float* Xr  = buf;                     //  X full: [0,8448) + [8448,16896)
  float* Xi  = buf + 8448;
  float* Fh  = buf;                     //  frames: [0,16426)

  const int tid = threadIdx.x;
  const int tl  = tid & 7;              // t within tile
  const int q   = tid >> 3;             // k1 (stage 1) / r (stage 2)

  // XCD-aware remap (R8): each XCD owns 32 contiguous t-tiles of one batch.
  const int id   = blockIdx.x;          // 0..2047
  const int xcd  = id & 7;
  const int slot = id >> 3;             // 0..255
  const int b    = slot >> 5;           // 0..7
  const int tile = xcd * 32 + (slot & 31);  // 0..255
  const int t0   = tile * TT;

  const float* re_p = in + ((size_t)b * 2 + 0) * ((size_t)FDIM * TDIM);
  const float* im_p = in + ((size_t)b * 2 + 1) * ((size_t)FDIM * TDIM);

  const float KS = (float)(exp((-1.0 / 0.65) * log(0.06)) / 2048.0);
  const float PE = 7.0f / 26.0f;

  // ---- Stage 1: load 4 mirror-paired rows, denorm+pack, stage W, 1 barrier --
  {
    int rows[4];
    if (tid) { rows[0] = tid; rows[1] = 1024 - tid;
               rows[2] = 256 + tid; rows[3] = 768 - tid; }
    else     { rows[0] = 0; rows[1] = 512; rows[2] = 256; rows[3] = 768; }

    float4 re[4][2], im[4][2];
    #pragma unroll
    for (int j = 0; j < 4; ++j) {
      #pragma unroll
      for (int h = 0; h < 2; ++h) {     // 16 loads, all in flight together
        re[j][h] = *(const float4*)(re_p + (size_t)rows[j] * TDIM + t0 + 4 * h);
        im[j][h] = *(const float4*)(im_p + (size_t)rows[j] * TDIM + t0 + 4 * h);
      }
    }
    #pragma unroll
    for (int j = 0; j < 4; ++j) {
      denorm4(re[j][0], im[j][0], PE, KS);
      denorm4(re[j][1], im[j][1], PE, KS);
    }
    const int rot = (tid >> 1) & 3;
    if (tid) {
      pack_pair8(Sri, tid, 1024 - tid, re[0], im[0], re[1], im[1], rot);
      pack_pair8(Sri, 256 + tid, 768 - tid, re[2], im[2], re[3], im[3], rot);
    } else {
      dc8(Sri, re[0], rot);                                    // k = 0
      pack_pair8(Sri, 512, 512, re[1], im[1], re[1], im[1], rot); // k = 512 self
      pack_pair8(Sri, 256, 768, re[2], im[2], re[3], im[3], rot); // pair
    }
  }
  __syncthreads();                      // staged W visible (vmcnt already 0)

  // ---- read W (32 b64, no phases, no special cases) + FFT32 over k2 ----
  float ar[32], ai[32];
  #pragma unroll
  for (int u = 0; u < 32; ++u) {        // k = q + 32u; k2 = u
    const float2 w = *(const float2*)(Sri + (q + 32 * u) * 16 + 2 * tl);
    ar[kBREV[u]] = w.x; ai[kBREV[u]] = w.y;
  }
  ifft32_core(ar, ai);
  __syncthreads();                      // staging dead; X may overwrite buf

  // ---- Transpose through FULL X (R14 verbatim) ----
  // Inter-stage twiddle e^{2 pi i q r/1024} by incremental rotation
  // (31-step recurrence err ~2e-6, negligible vs absmax threshold).
  {
    const float aq2 = 6.1359231515425649e-3f * (float)q;
    const float dc = __cosf(aq2), dsn = __sinf(aq2);
    float cs = 1.0f, sn = 0.0f;
    #pragma unroll
    for (int r = 0; r < 32; ++r) {
      Xr[XIDX(tl, q, r)] = cs * ar[r] - sn * ai[r];
      Xi[XIDX(tl, q, r)] = cs * ai[r] + sn * ar[r];
      const float ncs = cs * dc - sn * dsn;
      sn = cs * dsn + sn * dc;
      cs = ncs;
    }
  }
  __syncthreads();
  float zr[32], zi[32];
  #pragma unroll
  for (int i = 0; i < 32; ++i) {        // bit-reversed k1 load order
    zr[i] = Xr[XIDX(tl, kBREV[i], q)];
    zi[i] = Xi[XIDX(tl, kBREV[i], q)];
  }
  __syncthreads();                      // X dead; F tile may overwrite buf

  // ---- Stage 2: FFT32 over k1 ----
  ifft32_core(zr, zi);

  // ---- Full 8-frame tile (all threads active) + single-pass OLA (R14) ----
  #pragma unroll
  for (int s = 0; s < 32; ++s) {
    const int l0 = 2 * q + 64 * s;
    const float2 w2 = *(const float2*)(invw + l0);
    float2 fv; fv.x = zr[s] * w2.x; fv.y = zi[s] * w2.y;
    *(float2*)(Fh + tl * FSTR + l0) = fv;
  }
  __syncthreads();

  // ---- OLA: out[512*t' + j] = sum_c F[t'-c-t0][j + 512c] ----
  float* ob = out + (size_t)b * NTOT;
  for (int rel = 0; rel < 11; ++rel) {
    const int tp = t0 + rel;
    if (tp > 2047) break;
    #pragma unroll
    for (int half = 0; half < 2; ++half) {
      const int j = tid + 256 * half;   // lanes j-consecutive -> coalesced
      float v = 0.0f;
      #pragma unroll
      for (int cc = 0; cc < 4; ++cc) {
        const int tt = rel - cc;
        if (tt >= 0 && tt < TT) v += Fh[tt * FSTR + j + 512 * cc];
      }
      const int n = tp * 512 + j;
      if (rel >= 3 && rel <= 7) ob[n] = v;          // all 4 contributors in-block
      else atomicAdd(&ob[n], v);                     // tile boundary: 2 writers
    }
  }
}

extern "C" void kernel_launch(void* const* d_in, const int* in_sizes, int n_in,
                              void* d_out, int out_size, void* d_ws, size_t ws_size,
                              hipStream_t stream) {
  (void)in_sizes; (void)n_in; (void)d_ws; (void)ws_size;
  const float* in   = (const float*)d_in[0];
  const float* invw = (const float*)d_in[1];
  float* out = (float*)d_out;
  hipMemsetAsync(out, 0, (size_t)out_size * sizeof(float), stream);
  istft_fused<<<dim3(TDIM / TT * 8), 256, 0, stream>>>(in, invw, out);
}